// Round 1
// baseline (682.855 us; speedup 1.0000x reference)
//
#include <hip/hip_runtime.h>
#include <hip/hip_bf16.h>
#include <math.h>

// Problem constants
#define B_  4
#define L_  384
#define DS_ 384
#define DP_ 128
#define NB_ 4
#define FEAT_ (DS_ + 2*DP_)   // 640
#define LN_EPS_ 1e-5f

// ---------------------------------------------------------------------------
// Kernel M: normalize mask to int32 regardless of stored dtype.
// Detection: scan first n/4 dwords (safe: buffer holds >= n bytes).
//   all dwords in {0,1}           -> int32 layout
//   all dwords in {0,0x3F800000}  -> float32 layout
//   otherwise                     -> 1-byte bool layout
__global__ __launch_bounds__(256) void k_mask(const void* __restrict__ mask_raw,
                                              int* __restrict__ maskN, int n) {
    const unsigned int* dw = (const unsigned int*)mask_raw;
    int tid = threadIdx.x;
    int local_int = 1, local_flt = 1;
    for (int i = tid; i < n / 4; i += blockDim.x) {
        unsigned int v = dw[i];
        if (v != 0u && v != 1u) local_int = 0;
        if (v != 0u && v != 0x3F800000u) local_flt = 0;
    }
    int all_int = __syncthreads_and(local_int);
    int all_flt = __syncthreads_and(local_flt);
    if (all_int) {
        for (int i = tid; i < n; i += blockDim.x) maskN[i] = (dw[i] != 0u) ? 1 : 0;
    } else if (all_flt) {
        const float* f = (const float*)mask_raw;
        for (int i = tid; i < n; i += blockDim.x) maskN[i] = (f[i] != 0.0f) ? 1 : 0;
    } else {
        const unsigned char* by = (const unsigned char*)mask_raw;
        for (int i = tid; i < n; i += blockDim.x) maskN[i] = by[i] ? 1 : 0;
    }
}

// ---------------------------------------------------------------------------
// Kernel B: pair-branch row pass. One block per (b,i) row.
// 4 waves; each wave handles j = wave, wave+4, ... Lane owns 2 channels
// (float2), LN reduction is a pure intra-wave shfl_xor (64 lanes x 2ch = 128).
// Accumulates  rs_inter[b,i,:] = sum_j w_inter * LN(p_sym[b,i,j,:])
//              rs_intra[b,i,:] = sum_j w_intra_band * LN(p_sym[b,i,j,:])
// plus scalar denominators. Diagonal j==i: p_sym=0 -> LN(0)=b_z (weighted).
__global__ __launch_bounds__(256) void k_pair_rows(
    const float* __restrict__ pair, const float* __restrict__ gz,
    const float* __restrict__ bz, const int* __restrict__ chain,
    const int* __restrict__ maskN,
    float* __restrict__ rs_inter, float* __restrict__ rs_intra,
    float* __restrict__ den_inter, float* __restrict__ den_intra) {
    const int row = blockIdx.x;          // b*L + i
    const int b = row / L_, i = row % L_;
    const int tid = threadIdx.x;
    const int wave = tid >> 6;
    const int lane = tid & 63;
    const int ch2 = lane * 2;

    const int mi = maskN[b * L_ + i];
    const int ci = chain[b * L_ + i];
    const float g0 = gz[ch2], g1 = gz[ch2 + 1];
    const float bb0 = bz[ch2], bb1 = bz[ch2 + 1];

    const float* basA = pair + (size_t)row * L_ * DP_;                 // + j*DP
    const float* basB = pair + (size_t)b * L_ * L_ * DP_ + (size_t)i * DP_;  // + j*L*DP

    float acc_i0 = 0.f, acc_i1 = 0.f, acc_a0 = 0.f, acc_a1 = 0.f;
    float dI = 0.f, dA = 0.f;

    for (int j = wave; j < L_; j += 4) {
        float2 z1 = *(const float2*)(basA + (size_t)j * DP_ + ch2);
        float2 z2 = *(const float2*)(basB + (size_t)j * L_ * DP_ + ch2);
        float v0, v1;
        if (j == i) { v0 = 0.f; v1 = 0.f; }
        else { v0 = 0.5f * (z1.x + z2.x); v1 = 0.5f * (z1.y + z2.y); }
        // LayerNorm over 128 channels (intra-wave reduction)
        float s = v0 + v1, q = v0 * v0 + v1 * v1;
        #pragma unroll
        for (int off = 32; off; off >>= 1) {
            s += __shfl_xor(s, off);
            q += __shfl_xor(q, off);
        }
        const float mu = s * (1.0f / DP_);
        const float var = q * (1.0f / DP_) - mu * mu;
        const float rstd = rsqrtf(var + LN_EPS_);
        const float y0 = (v0 - mu) * rstd * g0 + bb0;
        const float y1 = (v1 - mu) * rstd * g1 + bb1;
        // weights
        const int mj = maskN[b * L_ + j];
        const int cj = chain[b * L_ + j];
        const int pm = mi & mj;
        const bool same = (ci == cj);
        int d = j - i; if (d < 0) d = -d;
        const float wI = (pm && !same) ? 1.f : 0.f;
        const float wA = (pm && same && d <= NB_) ? 1.f : 0.f;
        acc_i0 += wI * y0; acc_i1 += wI * y1;
        acc_a0 += wA * y0; acc_a1 += wA * y1;
        dI += wI; dA += wA;
    }

    __shared__ float smI[4][DP_], smA[4][DP_];
    __shared__ float smDI[4], smDA[4];
    smI[wave][ch2] = acc_i0; smI[wave][ch2 + 1] = acc_i1;
    smA[wave][ch2] = acc_a0; smA[wave][ch2 + 1] = acc_a1;
    if (lane == 0) { smDI[wave] = dI; smDA[wave] = dA; }
    __syncthreads();
    if (tid < DP_) {
        float vI = smI[0][tid] + smI[1][tid] + smI[2][tid] + smI[3][tid];
        float vA = smA[0][tid] + smA[1][tid] + smA[2][tid] + smA[3][tid];
        rs_inter[(size_t)row * DP_ + tid] = vI;
        rs_intra[(size_t)row * DP_ + tid] = vA;
    }
    if (tid == 0) {
        den_inter[row] = smDI[0] + smDI[1] + smDI[2] + smDI[3];
        den_intra[row] = smDA[0] + smDA[1] + smDA[2] + smDA[3];
    }
}

// ---------------------------------------------------------------------------
// Kernel S1: s = LN(seq_repr) @ W_seq, 4 rows per block.
#define SROWS_ 4
__global__ __launch_bounds__(384) void k_seq_proj(
    const float* __restrict__ seq, const float* __restrict__ gs,
    const float* __restrict__ bs, const float* __restrict__ W,
    float* __restrict__ s_rows) {
    const int row0 = blockIdx.x * SROWS_;
    const int tid = threadIdx.x;
    const int wave = tid >> 6, lane = tid & 63;
    __shared__ float xn[SROWS_][DS_];
    __shared__ float sSum[SROWS_][6], sSq[SROWS_][6];
    const float gg = gs[tid], bbv = bs[tid];
    #pragma unroll
    for (int r = 0; r < SROWS_; r++) {
        float x = seq[(size_t)(row0 + r) * DS_ + tid];
        float s = x, q = x * x;
        #pragma unroll
        for (int off = 32; off; off >>= 1) {
            s += __shfl_xor(s, off);
            q += __shfl_xor(q, off);
        }
        if (lane == 0) { sSum[r][wave] = s; sSq[r][wave] = q; }
        xn[r][tid] = x;
    }
    __syncthreads();
    float mu[SROWS_], rstd[SROWS_];
    #pragma unroll
    for (int r = 0; r < SROWS_; r++) {
        float ts = 0.f, tq = 0.f;
        #pragma unroll
        for (int w = 0; w < 6; w++) { ts += sSum[r][w]; tq += sSq[r][w]; }
        mu[r] = ts * (1.0f / DS_);
        float var = tq * (1.0f / DS_) - mu[r] * mu[r];
        rstd[r] = rsqrtf(var + LN_EPS_);
    }
    #pragma unroll
    for (int r = 0; r < SROWS_; r++)
        xn[r][tid] = (xn[r][tid] - mu[r]) * rstd[r] * gg + bbv;
    __syncthreads();
    float acc[SROWS_] = {0.f, 0.f, 0.f, 0.f};
    for (int k = 0; k < DS_; k++) {
        float w = W[(size_t)k * DS_ + tid];
        #pragma unroll
        for (int r = 0; r < SROWS_; r++) acc[r] += xn[r][k] * w;
    }
    #pragma unroll
    for (int r = 0; r < SROWS_; r++)
        s_rows[(size_t)(row0 + r) * DS_ + tid] = acc[r];
}

// ---------------------------------------------------------------------------
// Kernel S2: masked mean/max over L, gate, write s_feat into feat[0:384].
__global__ __launch_bounds__(384) void k_seq_reduce(
    const float* __restrict__ s_rows, const int* __restrict__ maskN,
    const float* __restrict__ Wgs, const float* __restrict__ bgs,
    float* __restrict__ feat) {
    const int b = blockIdx.x;
    const int ch = threadIdx.x;
    float sum = 0.f, mx = -INFINITY;
    int den = 0;
    for (int l = 0; l < L_; l++) {
        int m = maskN[b * L_ + l];
        float v = s_rows[(size_t)(b * L_ + l) * DS_ + ch];
        if (m) { sum += v; mx = fmaxf(mx, v); den++; }
    }
    const float fden = fmaxf((float)den, 1e-6f);
    const float smean = sum / fden;
    const float smax = (den > 0) ? mx : 0.f;   // isinf -> 0
    __shared__ float sMean[DS_], sMax[DS_];
    sMean[ch] = smean; sMax[ch] = smax;
    __syncthreads();
    float acc = bgs[ch];
    for (int k = 0; k < DS_; k++) {
        acc += sMax[k] * Wgs[(size_t)k * DS_ + ch]
             + sMean[k] * Wgs[(size_t)(k + DS_) * DS_ + ch];
    }
    const float gate = 1.f / (1.f + expf(-acc));
    feat[b * FEAT_ + ch] = smean + gate * (smax - smean);
}

// ---------------------------------------------------------------------------
// Kernel C1: per-row projection  proj[row,ch] = (rs_inter[row,:]@W_pair)/clip(den)
__global__ __launch_bounds__(128) void k_proj_rows(
    const float* __restrict__ rs_inter, const float* __restrict__ den_inter,
    const float* __restrict__ Wp, float* __restrict__ proj) {
    const int row = blockIdx.x;
    const int ch = threadIdx.x;
    __shared__ float rs[DP_];
    rs[ch] = rs_inter[(size_t)row * DP_ + ch];
    __syncthreads();
    float acc = 0.f;
    for (int k = 0; k < DP_; k++) acc += rs[k] * Wp[k * DP_ + ch];
    proj[(size_t)row * DP_ + ch] = acc / fmaxf(den_inter[row], 1e-6f);
}

// ---------------------------------------------------------------------------
// Kernel C2: pair-branch finalize: inter_mean, inter_peak, intra_compact,
// gate_z, writes feat[384:640].
__global__ __launch_bounds__(128) void k_pair_final(
    const float* __restrict__ rs_inter, const float* __restrict__ rs_intra,
    const float* __restrict__ den_inter, const float* __restrict__ den_intra,
    const float* __restrict__ proj, const float* __restrict__ Wp,
    const float* __restrict__ Wgz, const float* __restrict__ bgz,
    float* __restrict__ feat) {
    const int b = blockIdx.x;
    const int ch = threadIdx.x;
    float totI = 0.f, totA = 0.f, dI = 0.f, dA = 0.f, peak = -INFINITY;
    for (int i = 0; i < L_; i++) {
        size_t r = (size_t)(b * L_ + i);
        totI += rs_inter[r * DP_ + ch];
        totA += rs_intra[r * DP_ + ch];
        peak = fmaxf(peak, proj[r * DP_ + ch]);
        dI += den_inter[r];
        dA += den_intra[r];
    }
    __shared__ float sI[DP_], sA[DP_], sPk[DP_], sIM[DP_];
    sI[ch] = totI; sA[ch] = totA;
    __syncthreads();
    float accI = 0.f, accA = 0.f;
    for (int k = 0; k < DP_; k++) {
        accI += sI[k] * Wp[k * DP_ + ch];
        accA += sA[k] * Wp[k * DP_ + ch];
    }
    const float im = accI / fmaxf(dI, 1e-6f);
    const float ic = accA / fmaxf(dA, 1e-6f);
    sPk[ch] = peak; sIM[ch] = im;
    __syncthreads();
    float acc = bgz[ch];
    for (int k = 0; k < DP_; k++) {
        acc += sPk[k] * Wgz[k * DP_ + ch] + sIM[k] * Wgz[(k + DP_) * DP_ + ch];
    }
    const float gate = 1.f / (1.f + expf(-acc));
    feat[b * FEAT_ + DS_ + ch] = im + gate * (sPk[ch] - im);
    feat[b * FEAT_ + DS_ + DP_ + ch] = ic;
}

// ---------------------------------------------------------------------------
// Kernel F: final MLP head. One block (64 threads) per batch element.
__global__ __launch_bounds__(64) void k_head(
    const float* __restrict__ feat, const float* __restrict__ W1,
    const float* __restrict__ b1, const float* __restrict__ W2,
    const float* __restrict__ b2, float* __restrict__ out) {
    const int b = blockIdx.x;
    const int h = threadIdx.x;
    float acc = b1[h];
    for (int k = 0; k < FEAT_; k++) acc += feat[b * FEAT_ + k] * W1[k * 64 + h];
    float hr = fmaxf(acc, 0.f);
    float p = hr * W2[h];
    #pragma unroll
    for (int off = 32; off; off >>= 1) p += __shfl_xor(p, off);
    if (h == 0) out[b] = 1.f / (1.f + expf(-(p + b2[0])));
}

// ---------------------------------------------------------------------------
extern "C" void kernel_launch(void* const* d_in, const int* in_sizes, int n_in,
                              void* d_out, int out_size, void* d_ws, size_t ws_size,
                              hipStream_t stream) {
    const float* seq    = (const float*)d_in[0];
    const float* pair   = (const float*)d_in[1];
    const float* ln_s_g = (const float*)d_in[2];
    const float* ln_s_b = (const float*)d_in[3];
    const float* ln_z_g = (const float*)d_in[4];
    const float* ln_z_b = (const float*)d_in[5];
    const float* W_seq  = (const float*)d_in[6];
    const float* W_pair = (const float*)d_in[7];
    const float* W_gs   = (const float*)d_in[8];
    const float* b_gs   = (const float*)d_in[9];
    const float* W_gz   = (const float*)d_in[10];
    const float* b_gz   = (const float*)d_in[11];
    const float* W1     = (const float*)d_in[12];
    const float* b1     = (const float*)d_in[13];
    const float* W2     = (const float*)d_in[14];
    const float* b2     = (const float*)d_in[15];
    const int*   chain  = (const int*)d_in[16];
    const void*  mask   = d_in[17];
    float* out = (float*)d_out;

    // workspace layout (all 4-byte aligned)
    char* ws = (char*)d_ws;
    int* maskN = (int*)ws;              ws += (size_t)B_ * L_ * sizeof(int);
    float* rs_inter = (float*)ws;       ws += (size_t)B_ * L_ * DP_ * sizeof(float);
    float* rs_intra = (float*)ws;       ws += (size_t)B_ * L_ * DP_ * sizeof(float);
    float* den_inter = (float*)ws;      ws += (size_t)B_ * L_ * sizeof(float);
    float* den_intra = (float*)ws;      ws += (size_t)B_ * L_ * sizeof(float);
    float* proj = (float*)ws;           ws += (size_t)B_ * L_ * DP_ * sizeof(float);
    float* s_rows = (float*)ws;         ws += (size_t)B_ * L_ * DS_ * sizeof(float);
    float* feat = (float*)ws;           ws += (size_t)B_ * FEAT_ * sizeof(float);

    const int nMask = B_ * L_;

    k_mask<<<1, 256, 0, stream>>>(mask, maskN, nMask);
    k_pair_rows<<<B_ * L_, 256, 0, stream>>>(pair, ln_z_g, ln_z_b, chain, maskN,
                                             rs_inter, rs_intra, den_inter, den_intra);
    k_seq_proj<<<(B_ * L_) / SROWS_, 384, 0, stream>>>(seq, ln_s_g, ln_s_b, W_seq, s_rows);
    k_seq_reduce<<<B_, 384, 0, stream>>>(s_rows, maskN, W_gs, b_gs, feat);
    k_proj_rows<<<B_ * L_, 128, 0, stream>>>(rs_inter, den_inter, W_pair, proj);
    k_pair_final<<<B_, 128, 0, stream>>>(rs_inter, rs_intra, den_inter, den_intra,
                                         proj, W_pair, W_gz, b_gz, feat);
    k_head<<<B_, 64, 0, stream>>>(feat, W1, b1, W2, b2, out);
}